// Round 6
// baseline (1748.616 us; speedup 1.0000x reference)
//
#include <hip/hip_runtime.h>
#include <hip/hip_bf16.h>

typedef _Float16 f16;
typedef _Float16 f16v2 __attribute__((ext_vector_type(2)));
typedef _Float16 f16v4 __attribute__((ext_vector_type(4)));

#define BB   2
#define LL   21
#define HH   512
#define WW   512
#define RR   20
#define NCH  84            // planes per batch: p(21), Ic*p(63); later b,a
#define HW   (HH*WW)
#define VSEG 64            // rows per vbox strip

__device__ __forceinline__ float nrminv(int x, int y) {
    int cx = min(x + RR, WW - 1) - max(x - RR, 0) + 1;
    int cy = min(y + RR, HH - 1) - max(y - RR, 0) + 1;
    return 1.0f / (float)(cx * cy);
}

// ---- vertical box: compact planes src->dst, thread = 4 columns, no LDS -----
template <typename T, typename V4>
__global__ __launch_bounds__(128) void vbox_k(const T* __restrict__ src,
                                              T* __restrict__ dst) {
    int pp = blockIdx.y;
    int y0 = blockIdx.x * VSEG;
    const T* s = src + (size_t)pp * HW + threadIdx.x * 4;
    T* d = dst + (size_t)pp * HW + threadIdx.x * 4;
    float s0 = 0.f, s1 = 0.f, s2 = 0.f, s3 = 0.f;
    int lo = y0 - RR; if (lo < 0) lo = 0;
    int hi = y0 + RR;
    for (int yy = lo; yy <= hi; ++yy) {
        V4 v = *(const V4*)(s + (size_t)yy * WW);
        s0 += (float)v.x; s1 += (float)v.y; s2 += (float)v.z; s3 += (float)v.w;
    }
    { V4 o; o.x = (T)s0; o.y = (T)s1; o.z = (T)s2; o.w = (T)s3;
      *(V4*)(d + (size_t)y0 * WW) = o; }
    #pragma unroll 4
    for (int y = y0 + 1; y < y0 + VSEG; ++y) {
        int ya = y + RR, ys = y - RR - 1;
        if (ya < HH) {
            V4 v = *(const V4*)(s + (size_t)ya * WW);
            s0 += (float)v.x; s1 += (float)v.y; s2 += (float)v.z; s3 += (float)v.w;
        }
        if (ys >= 0) {
            V4 v = *(const V4*)(s + (size_t)ys * WW);
            s0 -= (float)v.x; s1 -= (float)v.y; s2 -= (float)v.z; s3 -= (float)v.w;
        }
        V4 o; o.x = (T)s0; o.y = (T)s1; o.z = (T)s2; o.w = (T)s3;
        *(V4*)(d + (size_t)y * WW) = o;
    }
}

// ---- horizontal window helpers: NPX outputs, raw covers [x0-24, ...) -------
template <int NPX, typename T, typename V4>
__device__ __forceinline__ void load_win(const T* __restrict__ srow, int x0,
                                         float* __restrict__ raw) {
    constexpr int NC = (NPX + 44 + 3) / 4;       // 8 -> 13, 16 -> 15
    #pragma unroll
    for (int c = 0; c < NC; ++c) {
        int st = x0 - 24 + 4 * c;
        if (st >= 0 && st < WW) {
            V4 v = *(const V4*)(srow + st);
            raw[4*c+0] = (float)v.x; raw[4*c+1] = (float)v.y;
            raw[4*c+2] = (float)v.z; raw[4*c+3] = (float)v.w;
        } else {
            raw[4*c+0] = 0.f; raw[4*c+1] = 0.f; raw[4*c+2] = 0.f; raw[4*c+3] = 0.f;
        }
    }
}
template <int NPX>
__device__ __forceinline__ void slideN(const float* __restrict__ raw,
                                       float* __restrict__ res) {
    float sum = 0.f;
    #pragma unroll
    for (int j = 4; j <= 44; ++j) sum += raw[j];   // [x0-20, x0+20]
    res[0] = sum;
    #pragma unroll
    for (int k = 1; k < NPX; ++k) { sum += raw[k+44] - raw[k+3]; res[k] = sum; }
}

// ---- plain horizontal box (init, fp32): 16 px/thread -----------------------
template <typename T, typename V4>
__global__ __launch_bounds__(256) void hbox_k(const T* __restrict__ src,
                                              T* __restrict__ dst) {
    int pp = blockIdx.y;
    int row = blockIdx.x * 8 + (threadIdx.x >> 5);
    int x0 = (threadIdx.x & 31) << 4;
    const T* srow = src + (size_t)pp * HW + (size_t)row * WW;
    float raw[60], res[16];
    load_win<16, T, V4>(srow, x0, raw);
    slideN<16>(raw, res);
    T* drow = dst + (size_t)pp * HW + (size_t)row * WW + x0;
    #pragma unroll
    for (int g = 0; g < 4; ++g) {
        V4 o; o.x = (T)res[4*g]; o.y = (T)res[4*g+1];
        o.z = (T)res[4*g+2]; o.w = (T)res[4*g+3];
        *(V4*)(drow + 4*g) = o;
    }
}

// ---- phase-1: hbox of (p, Ip0..2) + fused 3x3 solve -> b, a (8 px/thr) -----
__global__ __launch_bounds__(256) void hbox_solve_k(const f16* __restrict__ Vb,
                                                    f16* __restrict__ U,
                                                    const float* __restrict__ Ainv,
                                                    const float* __restrict__ mI) {
    int bl = blockIdx.y;
    int b = bl / LL, l = bl - b * LL;
    int row = blockIdx.x * 4 + (threadIdx.x >> 6);
    int x0 = (threadIdx.x & 63) << 3;
    float res[4][8];
    #pragma unroll
    for (int c = 0; c < 4; ++c) {
        int ch = (c == 0) ? l : (LL + (c - 1) * LL + l);
        const f16* srow = Vb + (size_t)(b * NCH + ch) * HW + (size_t)row * WW;
        float raw[52];
        load_win<8, f16, f16v4>(srow, x0, raw);
        slideN<8>(raw, res[c]);
    }
    size_t pixb = (size_t)row * WW + x0;
    size_t ab = (size_t)b * 6 * HW + pixb;
    size_t mb = (size_t)b * 3 * HW + pixb;
    #pragma unroll
    for (int g = 0; g < 2; ++g) {
        float iv[6][4], mi[3][4];
        #pragma unroll
        for (int j = 0; j < 6; ++j) {
            float4 v = *(const float4*)(Ainv + ab + (size_t)j * HW + 4 * g);
            iv[j][0] = v.x; iv[j][1] = v.y; iv[j][2] = v.z; iv[j][3] = v.w;
        }
        #pragma unroll
        for (int j = 0; j < 3; ++j) {
            float4 v = *(const float4*)(mI + mb + (size_t)j * HW + 4 * g);
            mi[j][0] = v.x; mi[j][1] = v.y; mi[j][2] = v.z; mi[j][3] = v.w;
        }
        #pragma unroll
        for (int e = 0; e < 4; ++e) {
            int k = 4 * g + e;
            float nrm = nrminv(x0 + k, row);
            float mp   = res[0][k] * nrm;
            float cov0 = res[1][k] * nrm - mi[0][e] * mp;
            float cov1 = res[2][k] * nrm - mi[1][e] * mp;
            float cov2 = res[3][k] * nrm - mi[2][e] * mp;
            float a0 = iv[0][e] * cov0 + iv[1][e] * cov1 + iv[2][e] * cov2;
            float a1 = iv[1][e] * cov0 + iv[3][e] * cov1 + iv[4][e] * cov2;
            float a2 = iv[2][e] * cov0 + iv[4][e] * cov1 + iv[5][e] * cov2;
            float bb = mp - (a0 * mi[0][e] + a1 * mi[1][e] + a2 * mi[2][e]);
            res[0][k] = bb; res[1][k] = a0; res[2][k] = a1; res[3][k] = a2;
        }
    }
    #pragma unroll
    for (int c = 0; c < 4; ++c) {
        int ch = (c == 0) ? l : (LL + (c - 1) * LL + l);
        f16* drow = U + (size_t)(b * NCH + ch) * HW + pixb;
        #pragma unroll
        for (int g = 0; g < 2; ++g) {
            f16v4 o; o.x = (f16)res[c][4*g];   o.y = (f16)res[c][4*g+1];
            o.z = (f16)res[c][4*g+2]; o.w = (f16)res[c][4*g+3];
            *(f16v4*)(drow + 4 * g) = o;
        }
    }
}

// ---- phase-2: hbox of (b, a0..2) + fused q combine -> q plane (8 px/thr) ---
__global__ __launch_bounds__(256) void hbox_q_k(const f16* __restrict__ Vb,
                                                const float* __restrict__ Refs,
                                                f16* __restrict__ Q) {
    int bl = blockIdx.y;
    int b = bl / LL, l = bl - b * LL;
    int row = blockIdx.x * 4 + (threadIdx.x >> 6);
    int x0 = (threadIdx.x & 63) << 3;
    float res[4][8];
    #pragma unroll
    for (int c = 0; c < 4; ++c) {
        int ch = (c == 0) ? l : (LL + (c - 1) * LL + l);
        const f16* srow = Vb + (size_t)(b * NCH + ch) * HW + (size_t)row * WW;
        float raw[52];
        load_win<8, f16, f16v4>(srow, x0, raw);
        slideN<8>(raw, res[c]);
    }
    size_t pixb = (size_t)row * WW + x0;
    f16* qrow = Q + (size_t)(b * LL + l) * HW + pixb;
    #pragma unroll
    for (int g = 0; g < 2; ++g) {
        float4 i0 = *(const float4*)(Refs + ((size_t)b * 3 + 0) * HW + pixb + 4 * g);
        float4 i1 = *(const float4*)(Refs + ((size_t)b * 3 + 1) * HW + pixb + 4 * g);
        float4 i2 = *(const float4*)(Refs + ((size_t)b * 3 + 2) * HW + pixb + 4 * g);
        float ic0[4] = {i0.x, i0.y, i0.z, i0.w};
        float ic1[4] = {i1.x, i1.y, i1.z, i1.w};
        float ic2[4] = {i2.x, i2.y, i2.z, i2.w};
        f16v4 o;
        f16 tmpo[4];
        #pragma unroll
        for (int e = 0; e < 4; ++e) {
            int k = 4 * g + e;
            float nrm = nrminv(x0 + k, row);
            float q = (res[0][k] + res[1][k] * ic0[e] + res[2][k] * ic1[e]
                       + res[3][k] * ic2[e]) * nrm;
            tmpo[e] = (f16)q;
        }
        o.x = tmpo[0]; o.y = tmpo[1]; o.z = tmpo[2]; o.w = tmpo[3];
        *(f16v4*)(qrow + 4 * g) = o;
    }
}

// ---- products: I and I*I into 9-plane/b fp32 compact buffer ----------------
__global__ __launch_bounds__(256) void prod_k(float* __restrict__ Pf,
                                              const float* __restrict__ Refs) {
    int idx = blockIdx.x * 256 + threadIdx.x;
    int b = idx >> 18, pix = idx & (HW - 1);
    float I0 = Refs[((size_t)b * 3 + 0) * HW + pix];
    float I1 = Refs[((size_t)b * 3 + 1) * HW + pix];
    float I2 = Refs[((size_t)b * 3 + 2) * HW + pix];
    size_t base = (size_t)b * 9 * HW + pix;
    Pf[base + (size_t)0 * HW] = I0;
    Pf[base + (size_t)1 * HW] = I1;
    Pf[base + (size_t)2 * HW] = I2;
    Pf[base + (size_t)3 * HW] = I0 * I0;
    Pf[base + (size_t)4 * HW] = I0 * I1;
    Pf[base + (size_t)5 * HW] = I0 * I2;
    Pf[base + (size_t)6 * HW] = I1 * I1;
    Pf[base + (size_t)7 * HW] = I1 * I2;
    Pf[base + (size_t)8 * HW] = I2 * I2;
}

// ---- prep: boxed(I,II) fp32 -> Ainv (6 planes), mI (3 planes) --------------
__global__ __launch_bounds__(256) void prep_k(const float* __restrict__ Bf,
                                              float* __restrict__ Ainv, float* __restrict__ mI,
                                              const float* __restrict__ epsp) {
    int idx = blockIdx.x * 256 + threadIdx.x;
    int b = idx >> 18, pix = idx & (HW - 1);
    int x = pix & (WW - 1), y = pix >> 9;
    float nrm = nrminv(x, y);
    float eps = epsp[0];
    size_t base = (size_t)b * 9 * HW + pix;
    float m0 = Bf[base + (size_t)0 * HW] * nrm;
    float m1 = Bf[base + (size_t)1 * HW] * nrm;
    float m2 = Bf[base + (size_t)2 * HW] * nrm;
    float v00 = Bf[base + (size_t)3 * HW] * nrm - m0 * m0 + eps;
    float v01 = Bf[base + (size_t)4 * HW] * nrm - m0 * m1;
    float v02 = Bf[base + (size_t)5 * HW] * nrm - m0 * m2;
    float v11 = Bf[base + (size_t)6 * HW] * nrm - m1 * m1 + eps;
    float v12 = Bf[base + (size_t)7 * HW] * nrm - m1 * m2;
    float v22 = Bf[base + (size_t)8 * HW] * nrm - m2 * m2 + eps;
    float c00 = v11 * v22 - v12 * v12;
    float c01 = v02 * v12 - v01 * v22;
    float c02 = v01 * v12 - v02 * v11;
    float c11 = v00 * v22 - v02 * v02;
    float c12 = v01 * v02 - v00 * v12;
    float c22 = v00 * v11 - v01 * v01;
    float det = v00 * c00 + v01 * c01 + v02 * c02;
    float id = 1.0f / det;
    size_t ab = (size_t)b * 6 * HW + pix;
    Ainv[ab + (size_t)0 * HW] = c00 * id;
    Ainv[ab + (size_t)1 * HW] = c01 * id;
    Ainv[ab + (size_t)2 * HW] = c02 * id;
    Ainv[ab + (size_t)3 * HW] = c11 * id;
    Ainv[ab + (size_t)4 * HW] = c12 * id;
    Ainv[ab + (size_t)5 * HW] = c22 * id;
    size_t mb = (size_t)b * 3 * HW + pix;
    mI[mb]                  = m0;
    mI[mb + (size_t)HW]     = m1;
    mI[mb + (size_t)2 * HW] = m2;
}

// ---- fused: E=E0+q, Q=softmax(-E), p=W.Q, Ip (2 px/thread) -----------------
// mode 0: Q0 from E0 only; 1: mid; 2: last (fp32 Q -> out)
__global__ __launch_bounds__(256) void e_k(const f16* __restrict__ Q,
                                           f16* __restrict__ pout,
                                           const float* __restrict__ E0,
                                           const float* __restrict__ Refs,
                                           const float* __restrict__ Wf,
                                           float* __restrict__ out, int mode) {
    int idx = blockIdx.x * 256 + threadIdx.x;
    int b = idx >> 17;
    int pix = (idx & (HW / 2 - 1)) * 2;
    size_t base  = (size_t)b * NCH * HW + pix;
    size_t ebase = (size_t)b * LL * HW + pix;
    float2 Ic0 = *(const float2*)(Refs + ((size_t)b * 3 + 0) * HW + pix);
    float2 Ic1 = *(const float2*)(Refs + ((size_t)b * 3 + 1) * HW + pix);
    float2 Ic2 = *(const float2*)(Refs + ((size_t)b * 3 + 2) * HW + pix);
    float Ev0[LL], Ev1[LL];
    float m0 = -1e30f, m1 = -1e30f;
    #pragma unroll
    for (int l = 0; l < LL; ++l) {
        float2 e0 = *(const float2*)(E0 + ebase + (size_t)l * HW);
        float v0 = e0.x, v1 = e0.y;
        if (mode != 0) {
            f16v2 qv = *(const f16v2*)(Q + ebase + (size_t)l * HW);
            v0 += (float)qv.x; v1 += (float)qv.y;
        }
        Ev0[l] = -v0; Ev1[l] = -v1;
        m0 = fmaxf(m0, Ev0[l]); m1 = fmaxf(m1, Ev1[l]);
    }
    float s0 = 0.f, s1 = 0.f;
    #pragma unroll
    for (int l = 0; l < LL; ++l) {
        Ev0[l] = __expf(Ev0[l] - m0); s0 += Ev0[l];
        Ev1[l] = __expf(Ev1[l] - m1); s1 += Ev1[l];
    }
    float i0 = 1.0f / s0, i1 = 1.0f / s1;
    if (mode == 2) {
        #pragma unroll
        for (int l = 0; l < LL; ++l) {
            float2 o; o.x = Ev0[l] * i0; o.y = Ev1[l] * i1;
            *(float2*)(out + ebase + (size_t)l * HW) = o;
        }
    } else {
        #pragma unroll
        for (int l = 0; l < LL; ++l) { Ev0[l] *= i0; Ev1[l] *= i1; }
        #pragma unroll
        for (int l = 0; l < LL; ++l) {
            float p0 = 0.f, p1 = 0.f;
            #pragma unroll
            for (int m = 0; m < LL; ++m) {
                float w = Wf[l * LL + m];
                p0 += w * Ev0[m]; p1 += w * Ev1[m];
            }
            f16v2 o;
            o.x = (f16)p0; o.y = (f16)p1;
            *(f16v2*)(pout + base + (size_t)l * HW) = o;
            o.x = (f16)(p0 * Ic0.x); o.y = (f16)(p1 * Ic0.y);
            *(f16v2*)(pout + base + (size_t)(LL + 0*LL + l) * HW) = o;
            o.x = (f16)(p0 * Ic1.x); o.y = (f16)(p1 * Ic1.y);
            *(f16v2*)(pout + base + (size_t)(LL + 1*LL + l) * HW) = o;
            o.x = (f16)(p0 * Ic2.x); o.y = (f16)(p1 * Ic2.y);
            *(f16v2*)(pout + base + (size_t)(LL + 2*LL + l) * HW) = o;
        }
    }
}

// ---- host ------------------------------------------------------------------
extern "C" void kernel_launch(void* const* d_in, const int* in_sizes, int n_in,
                              void* d_out, int out_size, void* d_ws, size_t ws_size,
                              hipStream_t stream) {
    const float* E0   = (const float*)d_in[0];
    const float* Refs = (const float*)d_in[1];
    const float* Wmu  = (const float*)d_in[2];
    const float* epsp = (const float*)d_in[3];
    float* out = (float*)d_out;

    size_t Ub = (size_t)BB * NCH * HW * 2;   // 84 MB fp16
    size_t Ab = (size_t)BB * 6 * HW * 4;     // 12 MB fp32
    size_t Mb = (size_t)BB * 3 * HW * 4;     // 6 MB fp32
    char* ws = (char*)d_ws;
    f16*   U    = (f16*)ws;
    f16*   V    = (f16*)(ws + Ub);
    float* Ainv = (float*)(ws + 2 * Ub);
    float* mI   = (float*)(ws + 2 * Ub + Ab);
    f16*   Qb   = (f16*)(ws + 2 * Ub + Ab + Mb);  // 21 fp16 q planes x BB (22 MB)
    float* Uf   = (float*)U;                 // init fp32 alias (9 planes/b)
    float* Vf   = (float*)V;

    int nblk = (BB * HW) / 256;
    // init: I, I*I -> 2D box (fp32) -> Ainv, mI
    prod_k<<<nblk, 256, 0, stream>>>(Uf, Refs);
    vbox_k<float, float4><<<dim3(HH / VSEG, BB * 9), 128, 0, stream>>>(Uf, Vf);
    hbox_k<float, float4><<<dim3(HH / 8, BB * 9), 256, 0, stream>>>(Vf, Uf);
    prep_k<<<nblk, 256, 0, stream>>>(Uf, Ainv, mI, epsp);
    // Q0 -> p, Ip into U (mode 0 reads no Q)
    e_k<<<(BB * HW / 2) / 256, 256, 0, stream>>>(Qb, U, E0, Refs, Wmu, out, 0);

    for (int t = 1; t <= 5; ++t) {
        vbox_k<f16, f16v4><<<dim3(HH / VSEG, BB * NCH), 128, 0, stream>>>(U, V);
        hbox_solve_k<<<dim3(HH / 4, BB * LL), 256, 0, stream>>>(V, U, Ainv, mI);
        vbox_k<f16, f16v4><<<dim3(HH / VSEG, BB * NCH), 128, 0, stream>>>(U, V);
        hbox_q_k<<<dim3(HH / 4, BB * LL), 256, 0, stream>>>(V, Refs, Qb);
        e_k<<<(BB * HW / 2) / 256, 256, 0, stream>>>(Qb, U, E0, Refs, Wmu, out,
                                                     t == 5 ? 2 : 1);
    }
}

// Round 7
// 1495.357 us; speedup vs baseline: 1.1694x; 1.1694x over previous
//
#include <hip/hip_runtime.h>
#include <hip/hip_bf16.h>

typedef _Float16 f16;
typedef _Float16 f16v2 __attribute__((ext_vector_type(2)));
typedef _Float16 f16v4 __attribute__((ext_vector_type(4)));
typedef _Float16 f16v8 __attribute__((ext_vector_type(8)));

#define BB   2
#define LL   21
#define HH   512
#define WW   512
#define RR   20
#define NCH  84            // planes per batch: p(21), Ic*p(63); later b,a
#define HW   (HH*WW)
#define VSEG 64            // rows per strip, fp32 init vbox
#define VSEG2 32           // rows per strip, f16 vbox8

__device__ __forceinline__ float nrminv(int x, int y) {
    int cx = min(x + RR, WW - 1) - max(x - RR, 0) + 1;
    int cy = min(y + RR, HH - 1) - max(y - RR, 0) + 1;
    return 1.0f / (float)(cx * cy);
}

// ---- vertical box fp32 (init only): 4 cols/thread --------------------------
__global__ __launch_bounds__(128) void vboxf_k(const float* __restrict__ src,
                                               float* __restrict__ dst) {
    int pp = blockIdx.y;
    int y0 = blockIdx.x * VSEG;
    const float* s = src + (size_t)pp * HW + threadIdx.x * 4;
    float* d = dst + (size_t)pp * HW + threadIdx.x * 4;
    float s0 = 0.f, s1 = 0.f, s2 = 0.f, s3 = 0.f;
    int lo = y0 - RR; if (lo < 0) lo = 0;
    int hi = y0 + RR;
    for (int yy = lo; yy <= hi; ++yy) {
        float4 v = *(const float4*)(s + (size_t)yy * WW);
        s0 += v.x; s1 += v.y; s2 += v.z; s3 += v.w;
    }
    { float4 o = {s0, s1, s2, s3}; *(float4*)(d + (size_t)y0 * WW) = o; }
    #pragma unroll 4
    for (int y = y0 + 1; y < y0 + VSEG; ++y) {
        int ya = y + RR, ys = y - RR - 1;
        if (ya < HH) {
            float4 v = *(const float4*)(s + (size_t)ya * WW);
            s0 += v.x; s1 += v.y; s2 += v.z; s3 += v.w;
        }
        if (ys >= 0) {
            float4 v = *(const float4*)(s + (size_t)ys * WW);
            s0 -= v.x; s1 -= v.y; s2 -= v.z; s3 -= v.w;
        }
        float4 o = {s0, s1, s2, s3};
        *(float4*)(d + (size_t)y * WW) = o;
    }
}

// ---- vertical box f16: 8 cols/thread (16-B loads), 2 strips/block ----------
__global__ __launch_bounds__(128) void vbox8_k(const f16* __restrict__ src,
                                               f16* __restrict__ dst) {
    int pp = blockIdx.y;
    int lane = threadIdx.x & 63;
    int y0 = (blockIdx.x * 2 + (threadIdx.x >> 6)) * VSEG2;
    const f16* s = src + (size_t)pp * HW + lane * 8;
    f16* d = dst + (size_t)pp * HW + lane * 8;
    float acc[8];
    #pragma unroll
    for (int i = 0; i < 8; ++i) acc[i] = 0.f;
    int lo = y0 - RR; if (lo < 0) lo = 0;
    int hi = y0 + RR;                       // y0 <= 480 -> hi <= 500 < 512
    for (int yy = lo; yy <= hi; ++yy) {
        f16v8 v = *(const f16v8*)(s + (size_t)yy * WW);
        #pragma unroll
        for (int i = 0; i < 8; ++i) acc[i] += (float)v[i];
    }
    {
        f16v8 o;
        #pragma unroll
        for (int i = 0; i < 8; ++i) o[i] = (f16)acc[i];
        *(f16v8*)(d + (size_t)y0 * WW) = o;
    }
    #pragma unroll 4
    for (int y = y0 + 1; y < y0 + VSEG2; ++y) {
        int ya = y + RR, ys = y - RR - 1;
        if (ya < HH) {
            f16v8 v = *(const f16v8*)(s + (size_t)ya * WW);
            #pragma unroll
            for (int i = 0; i < 8; ++i) acc[i] += (float)v[i];
        }
        if (ys >= 0) {
            f16v8 v = *(const f16v8*)(s + (size_t)ys * WW);
            #pragma unroll
            for (int i = 0; i < 8; ++i) acc[i] -= (float)v[i];
        }
        f16v8 o;
        #pragma unroll
        for (int i = 0; i < 8; ++i) o[i] = (f16)acc[i];
        *(f16v8*)(d + (size_t)y * WW) = o;
    }
}

// ---- horizontal window helpers (16 outputs, raw[60] = [x0-24, x0+36)) ------
template <typename T, typename V4>
__device__ __forceinline__ void load_win16(const T* __restrict__ srow, int x0,
                                           float* __restrict__ raw) {
    #pragma unroll
    for (int c = 0; c < 15; ++c) {
        int st = x0 - 24 + 4 * c;
        if (st >= 0 && st < WW) {
            V4 v = *(const V4*)(srow + st);
            raw[4*c+0] = (float)v.x; raw[4*c+1] = (float)v.y;
            raw[4*c+2] = (float)v.z; raw[4*c+3] = (float)v.w;
        } else {
            raw[4*c+0] = 0.f; raw[4*c+1] = 0.f; raw[4*c+2] = 0.f; raw[4*c+3] = 0.f;
        }
    }
}
__device__ __forceinline__ void slide16(const float* __restrict__ raw,
                                        float* __restrict__ res) {
    float sum = 0.f;
    #pragma unroll
    for (int j = 4; j <= 44; ++j) sum += raw[j];   // [x0-20, x0+20]
    res[0] = sum;
    #pragma unroll
    for (int k = 1; k < 16; ++k) { sum += raw[k+44] - raw[k+3]; res[k] = sum; }
}

// ---- plain horizontal box (init, fp32): 16 px/thread -----------------------
__global__ __launch_bounds__(256) void hboxf_k(const float* __restrict__ src,
                                               float* __restrict__ dst) {
    int pp = blockIdx.y;
    int row = blockIdx.x * 8 + (threadIdx.x >> 5);
    int x0 = (threadIdx.x & 31) << 4;
    const float* srow = src + (size_t)pp * HW + (size_t)row * WW;
    float raw[60], res[16];
    load_win16<float, float4>(srow, x0, raw);
    slide16(raw, res);
    float* drow = dst + (size_t)pp * HW + (size_t)row * WW + x0;
    #pragma unroll
    for (int g = 0; g < 4; ++g) {
        float4 o = {res[4*g], res[4*g+1], res[4*g+2], res[4*g+3]};
        *(float4*)(drow + 4*g) = o;
    }
}

// ---- phase-1: hbox of (p, Ip0..2) + fused 3x3 solve -> b, a (16 px/thr) ----
__global__ __launch_bounds__(256) void hbox_solve_k(const f16* __restrict__ Vb,
                                                    f16* __restrict__ U,
                                                    const float* __restrict__ Ainv,
                                                    const float* __restrict__ mI) {
    int bl = blockIdx.y;
    int b = bl / LL, l = bl - b * LL;
    int row = blockIdx.x * 8 + (threadIdx.x >> 5);
    int x0 = (threadIdx.x & 31) << 4;
    float res[4][16];
    #pragma unroll
    for (int c = 0; c < 4; ++c) {
        int ch = (c == 0) ? l : (LL + (c - 1) * LL + l);
        const f16* srow = Vb + (size_t)(b * NCH + ch) * HW + (size_t)row * WW;
        float raw[60];
        load_win16<f16, f16v4>(srow, x0, raw);
        slide16(raw, res[c]);
    }
    size_t pixb = (size_t)row * WW + x0;
    size_t ab = (size_t)b * 6 * HW + pixb;
    size_t mb = (size_t)b * 3 * HW + pixb;
    #pragma unroll
    for (int g = 0; g < 4; ++g) {
        float iv[6][4], mi[3][4];
        #pragma unroll
        for (int j = 0; j < 6; ++j) {
            float4 v = *(const float4*)(Ainv + ab + (size_t)j * HW + 4 * g);
            iv[j][0] = v.x; iv[j][1] = v.y; iv[j][2] = v.z; iv[j][3] = v.w;
        }
        #pragma unroll
        for (int j = 0; j < 3; ++j) {
            float4 v = *(const float4*)(mI + mb + (size_t)j * HW + 4 * g);
            mi[j][0] = v.x; mi[j][1] = v.y; mi[j][2] = v.z; mi[j][3] = v.w;
        }
        #pragma unroll
        for (int e = 0; e < 4; ++e) {
            int k = 4 * g + e;
            float nrm = nrminv(x0 + k, row);
            float mp   = res[0][k] * nrm;
            float cov0 = res[1][k] * nrm - mi[0][e] * mp;
            float cov1 = res[2][k] * nrm - mi[1][e] * mp;
            float cov2 = res[3][k] * nrm - mi[2][e] * mp;
            float a0 = iv[0][e] * cov0 + iv[1][e] * cov1 + iv[2][e] * cov2;
            float a1 = iv[1][e] * cov0 + iv[3][e] * cov1 + iv[4][e] * cov2;
            float a2 = iv[2][e] * cov0 + iv[4][e] * cov1 + iv[5][e] * cov2;
            float bb = mp - (a0 * mi[0][e] + a1 * mi[1][e] + a2 * mi[2][e]);
            res[0][k] = bb; res[1][k] = a0; res[2][k] = a1; res[3][k] = a2;
        }
    }
    #pragma unroll
    for (int c = 0; c < 4; ++c) {
        int ch = (c == 0) ? l : (LL + (c - 1) * LL + l);
        f16* drow = U + (size_t)(b * NCH + ch) * HW + pixb;
        #pragma unroll
        for (int g = 0; g < 4; ++g) {
            f16v4 o; o.x = (f16)res[c][4*g];   o.y = (f16)res[c][4*g+1];
            o.z = (f16)res[c][4*g+2]; o.w = (f16)res[c][4*g+3];
            *(f16v4*)(drow + 4 * g) = o;
        }
    }
}

// ---- phase-2: hbox of (b, a0..2) + fused q combine -> q plane (16 px/thr) --
__global__ __launch_bounds__(256) void hbox_q_k(const f16* __restrict__ Vb,
                                                const float* __restrict__ Refs,
                                                f16* __restrict__ Q) {
    int bl = blockIdx.y;
    int b = bl / LL, l = bl - b * LL;
    int row = blockIdx.x * 8 + (threadIdx.x >> 5);
    int x0 = (threadIdx.x & 31) << 4;
    float res[4][16];
    #pragma unroll
    for (int c = 0; c < 4; ++c) {
        int ch = (c == 0) ? l : (LL + (c - 1) * LL + l);
        const f16* srow = Vb + (size_t)(b * NCH + ch) * HW + (size_t)row * WW;
        float raw[60];
        load_win16<f16, f16v4>(srow, x0, raw);
        slide16(raw, res[c]);
    }
    size_t pixb = (size_t)row * WW + x0;
    f16* qrow = Q + (size_t)(b * LL + l) * HW + pixb;
    #pragma unroll
    for (int g = 0; g < 4; ++g) {
        float4 i0 = *(const float4*)(Refs + ((size_t)b * 3 + 0) * HW + pixb + 4 * g);
        float4 i1 = *(const float4*)(Refs + ((size_t)b * 3 + 1) * HW + pixb + 4 * g);
        float4 i2 = *(const float4*)(Refs + ((size_t)b * 3 + 2) * HW + pixb + 4 * g);
        float ic0[4] = {i0.x, i0.y, i0.z, i0.w};
        float ic1[4] = {i1.x, i1.y, i1.z, i1.w};
        float ic2[4] = {i2.x, i2.y, i2.z, i2.w};
        f16 tmpo[4];
        #pragma unroll
        for (int e = 0; e < 4; ++e) {
            int k = 4 * g + e;
            float nrm = nrminv(x0 + k, row);
            float q = (res[0][k] + res[1][k] * ic0[e] + res[2][k] * ic1[e]
                       + res[3][k] * ic2[e]) * nrm;
            tmpo[e] = (f16)q;
        }
        f16v4 o; o.x = tmpo[0]; o.y = tmpo[1]; o.z = tmpo[2]; o.w = tmpo[3];
        *(f16v4*)(qrow + 4 * g) = o;
    }
}

// ---- products: I and I*I into 9-plane/b fp32 compact buffer ----------------
__global__ __launch_bounds__(256) void prod_k(float* __restrict__ Pf,
                                              const float* __restrict__ Refs) {
    int idx = blockIdx.x * 256 + threadIdx.x;
    int b = idx >> 18, pix = idx & (HW - 1);
    float I0 = Refs[((size_t)b * 3 + 0) * HW + pix];
    float I1 = Refs[((size_t)b * 3 + 1) * HW + pix];
    float I2 = Refs[((size_t)b * 3 + 2) * HW + pix];
    size_t base = (size_t)b * 9 * HW + pix;
    Pf[base + (size_t)0 * HW] = I0;
    Pf[base + (size_t)1 * HW] = I1;
    Pf[base + (size_t)2 * HW] = I2;
    Pf[base + (size_t)3 * HW] = I0 * I0;
    Pf[base + (size_t)4 * HW] = I0 * I1;
    Pf[base + (size_t)5 * HW] = I0 * I2;
    Pf[base + (size_t)6 * HW] = I1 * I1;
    Pf[base + (size_t)7 * HW] = I1 * I2;
    Pf[base + (size_t)8 * HW] = I2 * I2;
}

// ---- prep: boxed(I,II) fp32 -> Ainv (6 planes), mI (3 planes) --------------
__global__ __launch_bounds__(256) void prep_k(const float* __restrict__ Bf,
                                              float* __restrict__ Ainv, float* __restrict__ mI,
                                              const float* __restrict__ epsp) {
    int idx = blockIdx.x * 256 + threadIdx.x;
    int b = idx >> 18, pix = idx & (HW - 1);
    int x = pix & (WW - 1), y = pix >> 9;
    float nrm = nrminv(x, y);
    float eps = epsp[0];
    size_t base = (size_t)b * 9 * HW + pix;
    float m0 = Bf[base + (size_t)0 * HW] * nrm;
    float m1 = Bf[base + (size_t)1 * HW] * nrm;
    float m2 = Bf[base + (size_t)2 * HW] * nrm;
    float v00 = Bf[base + (size_t)3 * HW] * nrm - m0 * m0 + eps;
    float v01 = Bf[base + (size_t)4 * HW] * nrm - m0 * m1;
    float v02 = Bf[base + (size_t)5 * HW] * nrm - m0 * m2;
    float v11 = Bf[base + (size_t)6 * HW] * nrm - m1 * m1 + eps;
    float v12 = Bf[base + (size_t)7 * HW] * nrm - m1 * m2;
    float v22 = Bf[base + (size_t)8 * HW] * nrm - m2 * m2 + eps;
    float c00 = v11 * v22 - v12 * v12;
    float c01 = v02 * v12 - v01 * v22;
    float c02 = v01 * v12 - v02 * v11;
    float c11 = v00 * v22 - v02 * v02;
    float c12 = v01 * v02 - v00 * v12;
    float c22 = v00 * v11 - v01 * v01;
    float det = v00 * c00 + v01 * c01 + v02 * c02;
    float id = 1.0f / det;
    size_t ab = (size_t)b * 6 * HW + pix;
    Ainv[ab + (size_t)0 * HW] = c00 * id;
    Ainv[ab + (size_t)1 * HW] = c01 * id;
    Ainv[ab + (size_t)2 * HW] = c02 * id;
    Ainv[ab + (size_t)3 * HW] = c11 * id;
    Ainv[ab + (size_t)4 * HW] = c12 * id;
    Ainv[ab + (size_t)5 * HW] = c22 * id;
    size_t mb = (size_t)b * 3 * HW + pix;
    mI[mb]                  = m0;
    mI[mb + (size_t)HW]     = m1;
    mI[mb + (size_t)2 * HW] = m2;
}

// ---- fused: E=E0+q, Q=softmax(-E), p=W.Q, Ip (2 px/thread) -----------------
// mode 0: Q0 from E0 only; 1: mid; 2: last (fp32 Q -> out)
__global__ __launch_bounds__(256) void e_k(const f16* __restrict__ Q,
                                           f16* __restrict__ pout,
                                           const float* __restrict__ E0,
                                           const float* __restrict__ Refs,
                                           const float* __restrict__ Wf,
                                           float* __restrict__ out, int mode) {
    int idx = blockIdx.x * 256 + threadIdx.x;
    int b = idx >> 17;
    int pix = (idx & (HW / 2 - 1)) * 2;
    size_t base  = (size_t)b * NCH * HW + pix;
    size_t ebase = (size_t)b * LL * HW + pix;
    float2 Ic0 = *(const float2*)(Refs + ((size_t)b * 3 + 0) * HW + pix);
    float2 Ic1 = *(const float2*)(Refs + ((size_t)b * 3 + 1) * HW + pix);
    float2 Ic2 = *(const float2*)(Refs + ((size_t)b * 3 + 2) * HW + pix);
    float Ev0[LL], Ev1[LL];
    float m0 = -1e30f, m1 = -1e30f;
    #pragma unroll
    for (int l = 0; l < LL; ++l) {
        float2 e0 = *(const float2*)(E0 + ebase + (size_t)l * HW);
        float v0 = e0.x, v1 = e0.y;
        if (mode != 0) {
            f16v2 qv = *(const f16v2*)(Q + ebase + (size_t)l * HW);
            v0 += (float)qv.x; v1 += (float)qv.y;
        }
        Ev0[l] = -v0; Ev1[l] = -v1;
        m0 = fmaxf(m0, Ev0[l]); m1 = fmaxf(m1, Ev1[l]);
    }
    float s0 = 0.f, s1 = 0.f;
    #pragma unroll
    for (int l = 0; l < LL; ++l) {
        Ev0[l] = __expf(Ev0[l] - m0); s0 += Ev0[l];
        Ev1[l] = __expf(Ev1[l] - m1); s1 += Ev1[l];
    }
    float i0 = 1.0f / s0, i1 = 1.0f / s1;
    if (mode == 2) {
        #pragma unroll
        for (int l = 0; l < LL; ++l) {
            float2 o; o.x = Ev0[l] * i0; o.y = Ev1[l] * i1;
            *(float2*)(out + ebase + (size_t)l * HW) = o;
        }
    } else {
        #pragma unroll
        for (int l = 0; l < LL; ++l) { Ev0[l] *= i0; Ev1[l] *= i1; }
        #pragma unroll
        for (int l = 0; l < LL; ++l) {
            float p0 = 0.f, p1 = 0.f;
            #pragma unroll
            for (int m = 0; m < LL; ++m) {
                float w = Wf[l * LL + m];
                p0 += w * Ev0[m]; p1 += w * Ev1[m];
            }
            f16v2 o;
            o.x = (f16)p0; o.y = (f16)p1;
            *(f16v2*)(pout + base + (size_t)l * HW) = o;
            o.x = (f16)(p0 * Ic0.x); o.y = (f16)(p1 * Ic0.y);
            *(f16v2*)(pout + base + (size_t)(LL + 0*LL + l) * HW) = o;
            o.x = (f16)(p0 * Ic1.x); o.y = (f16)(p1 * Ic1.y);
            *(f16v2*)(pout + base + (size_t)(LL + 1*LL + l) * HW) = o;
            o.x = (f16)(p0 * Ic2.x); o.y = (f16)(p1 * Ic2.y);
            *(f16v2*)(pout + base + (size_t)(LL + 2*LL + l) * HW) = o;
        }
    }
}

// ---- host ------------------------------------------------------------------
extern "C" void kernel_launch(void* const* d_in, const int* in_sizes, int n_in,
                              void* d_out, int out_size, void* d_ws, size_t ws_size,
                              hipStream_t stream) {
    const float* E0   = (const float*)d_in[0];
    const float* Refs = (const float*)d_in[1];
    const float* Wmu  = (const float*)d_in[2];
    const float* epsp = (const float*)d_in[3];
    float* out = (float*)d_out;

    size_t Ub = (size_t)BB * NCH * HW * 2;   // 84 MB fp16
    size_t Ab = (size_t)BB * 6 * HW * 4;     // 12 MB fp32
    size_t Mb = (size_t)BB * 3 * HW * 4;     // 6 MB fp32
    char* ws = (char*)d_ws;
    f16*   U    = (f16*)ws;
    f16*   V    = (f16*)(ws + Ub);
    float* Ainv = (float*)(ws + 2 * Ub);
    float* mI   = (float*)(ws + 2 * Ub + Ab);
    f16*   Qb   = (f16*)(ws + 2 * Ub + Ab + Mb);  // 21 fp16 q planes x BB
    float* Uf   = (float*)U;                 // init fp32 alias (9 planes/b)
    float* Vf   = (float*)V;

    int nblk = (BB * HW) / 256;
    // init: I, I*I -> 2D box (fp32) -> Ainv, mI
    prod_k<<<nblk, 256, 0, stream>>>(Uf, Refs);
    vboxf_k<<<dim3(HH / VSEG, BB * 9), 128, 0, stream>>>(Uf, Vf);
    hboxf_k<<<dim3(HH / 8, BB * 9), 256, 0, stream>>>(Vf, Uf);
    prep_k<<<nblk, 256, 0, stream>>>(Uf, Ainv, mI, epsp);
    // Q0 -> p, Ip into U (mode 0 reads no Q)
    e_k<<<(BB * HW / 2) / 256, 256, 0, stream>>>(Qb, U, E0, Refs, Wmu, out, 0);

    for (int t = 1; t <= 5; ++t) {
        vbox8_k<<<dim3(HH / (2 * VSEG2), BB * NCH), 128, 0, stream>>>(U, V);
        hbox_solve_k<<<dim3(HH / 8, BB * LL), 256, 0, stream>>>(V, U, Ainv, mI);
        vbox8_k<<<dim3(HH / (2 * VSEG2), BB * NCH), 128, 0, stream>>>(U, V);
        hbox_q_k<<<dim3(HH / 8, BB * LL), 256, 0, stream>>>(V, Refs, Qb);
        e_k<<<(BB * HW / 2) / 256, 256, 0, stream>>>(Qb, U, E0, Refs, Wmu, out,
                                                     t == 5 ? 2 : 1);
    }
}